// Round 1
// 1140.480 us; speedup vs baseline: 1.3793x; 1.3793x over previous
//
#include <hip/hip_runtime.h>
#include <math.h>

#define CC 32
#define CHUNK 4096  // 256 threads * 16 elems, for the rptr scan

static inline int cdiv(long long a, int b) { return (int)((a + b - 1) / b); }

// ---------- degree (by src, float) + CSR count (by dst, int) in one pass ----------
__global__ void k_degcnt(const int* __restrict__ src, const int* __restrict__ dst,
                         float* __restrict__ deg, int* __restrict__ cnt, int E) {
  int e = blockIdx.x * blockDim.x + threadIdx.x;
  if (e < E) {
    atomicAdd(&deg[src[e]], 1.0f);
    atomicAdd(&cnt[dst[e]], 1);
  }
}

__global__ void k_dis(float* __restrict__ dis, int N) {
  int i = blockIdx.x * blockDim.x + threadIdx.x;
  if (i < N) {
    float d = dis[i];
    dis[i] = (d > 0.f) ? rsqrtf(fmaxf(d, 1.f)) : 0.f;
  }
}

// ---------- CSR build: chunk sums -> serial chunk scan -> per-chunk fill ----------
__global__ void k_chunksum(const int* __restrict__ cnt, int* __restrict__ csum, int N) {
  int base = blockIdx.x * CHUNK;
  int v = 0;
  for (int i = threadIdx.x; i < CHUNK; i += 256) {
    int idx = base + i;
    if (idx < N) v += cnt[idx];
  }
  for (int m = 32; m; m >>= 1) v += __shfl_xor(v, m);
  __shared__ int ws[4];
  if ((threadIdx.x & 63) == 0) ws[threadIdx.x >> 6] = v;
  __syncthreads();
  if (threadIdx.x == 0) csum[blockIdx.x] = ws[0] + ws[1] + ws[2] + ws[3];
}

__global__ void k_scancsum(int* __restrict__ csum, int nb, int* __restrict__ rptr,
                           int N, int E) {
  int acc = 0;
  for (int i = 0; i < nb; ++i) { int v = csum[i]; csum[i] = acc; acc += v; }
  rptr[N] = E;
}

// exclusive scan within chunk; writes rptr[i] and cursor (in-place over cnt)
__global__ void k_fillrptr(int* __restrict__ cnt, const int* __restrict__ csum,
                           int* __restrict__ rptr, int N) {
  int base = blockIdx.x * CHUNK + threadIdx.x * 16;
  int v[16];
  int tot = 0;
#pragma unroll
  for (int q = 0; q < 16; ++q) {
    int idx = base + q;
    v[q] = (idx < N) ? cnt[idx] : 0;
    tot += v[q];
  }
  __shared__ int sh[256];
  sh[threadIdx.x] = tot;
  __syncthreads();
  for (int off = 1; off < 256; off <<= 1) {
    int add = (threadIdx.x >= off) ? sh[threadIdx.x - off] : 0;
    __syncthreads();
    sh[threadIdx.x] += add;
    __syncthreads();
  }
  int excl = sh[threadIdx.x] - tot + csum[blockIdx.x];
#pragma unroll
  for (int q = 0; q < 16; ++q) {
    int idx = base + q;
    if (idx < N) { rptr[idx] = excl; cnt[idx] = excl; }
    excl += v[q];
  }
}

__global__ void k_fill(const int* __restrict__ src, const int* __restrict__ dst,
                       const float* __restrict__ dis, int* __restrict__ cursor,
                       int* __restrict__ ssrc, float* __restrict__ sw, int E) {
  int e = blockIdx.x * blockDim.x + threadIdx.x;
  if (e >= E) return;
  int s = src[e], d = dst[e];
  int p = atomicAdd(&cursor[d], 1);
  ssrc[p] = s;
  sw[p] = -dis[s] * dis[d];
}

// ---------- fused Cheb step: gather-prop + recurrence + out += Tx@W ----------
// one 32-lane group per node; lane = channel
__global__ void k_cheb(const float* __restrict__ x_in, const float* __restrict__ x_sub,
                       const int* __restrict__ rptr, const int* __restrict__ ssrc,
                       const float* __restrict__ sw, const float* __restrict__ W,
                       float scale, float* __restrict__ tx_out, float* __restrict__ out,
                       int N) {
  __shared__ float wl[1024];
  for (int i = threadIdx.x; i < 1024; i += 256) wl[i] = W[i];
  __syncthreads();
  int node = blockIdx.x * 8 + (threadIdx.x >> 5);
  int lane = threadIdx.x & 31;
  if (node >= N) return;
  int beg = rptr[node], end = rptr[node + 1];
  float t = 0.f;
  for (int base = beg; base < end; base += 32) {
    int rem = end - base;
    int sj = 0; float wj = 0.f;
    if (lane < rem) { sj = ssrc[base + lane]; wj = sw[base + lane]; }
    int cnt = rem < 32 ? rem : 32;
#pragma unroll 4
    for (int q = 0; q < cnt; ++q) {
      int s = __shfl(sj, q, 32);
      float w = __shfl(wj, q, 32);
      t += w * x_in[(long long)s * 32 + lane];
    }
  }
  float txn = scale * t;
  if (x_sub) txn -= x_sub[(long long)node * 32 + lane];
  long long o = (long long)node * 32 + lane;
  tx_out[o] = txn;
  float acc = 0.f;
#pragma unroll
  for (int q = 0; q < 32; ++q)
    acc += __shfl(txn, q, 32) * wl[q * 32 + lane];
  out[o] += acc;
}

// out[i][j] (32-wide rows in T, OUTC-wide rows in out) (+)= T[i][:] @ W[32][OUTC]
template <int OUTC>
__global__ void k_gemm(const float* __restrict__ T, const float* __restrict__ W,
                       float* __restrict__ out, int N, int accumulate) {
  __shared__ float w[32 * OUTC];
  for (int i = threadIdx.x; i < 32 * OUTC; i += blockDim.x) w[i] = W[i];
  __syncthreads();
  const int ROWS = 256 / OUTC;
  int row = blockIdx.x * ROWS + threadIdx.x / OUTC;
  int col = threadIdx.x % OUTC;
  if (row >= N) return;
  const float* tr = T + (long long)row * 32;
  float acc = 0.f;
#pragma unroll
  for (int c = 0; c < 32; ++c) acc += tr[c] * w[c * OUTC + col];
  float* o = out + (long long)row * OUTC + col;
  if (accumulate) *o += acc; else *o = acc;
}

__global__ void k_chebinit(float* __restrict__ out, const float* __restrict__ b, int n) {
  int i = blockIdx.x * blockDim.x + threadIdx.x;
  if (i < n) out[i] = b[i & 31];
}

// ---------- SuperGAT ----------
__global__ void k_mxinit(unsigned* __restrict__ mx, int n) {
  int i = blockIdx.x * blockDim.x + threadIdx.x;
  if (i < n) mx[i] = 0x007FFFFFu;  // encode(-inf)
}

__device__ inline unsigned enc_f(float f) {
  unsigned u = __float_as_uint(f);
  return u ^ ((u & 0x80000000u) ? 0xFFFFFFFFu : 0x80000000u);
}
__device__ inline float dec_f(unsigned k) {
  return (k & 0x80000000u) ? __uint_as_float(k ^ 0x80000000u) : __uint_as_float(~k);
}

// 8-lane cooperative groups: one group per (edge, head); edges >= E are self-loops
__global__ void k_alpha(const float* __restrict__ h, const int* __restrict__ src,
                        const int* __restrict__ dst, const float* __restrict__ attl,
                        const float* __restrict__ attr, float* __restrict__ alpha,
                        unsigned* __restrict__ mx, int E, int N) {
  int tid = blockIdx.x * blockDim.x + threadIdx.x;
  int g = tid >> 3;         // (edge, head) index
  int q = tid & 7;          // float4 slice within the 128B segment
  int tot = (E + N) * 2;
  if (g >= tot) return;
  int e = g >> 1, hd = g & 1;
  int s = (e < E) ? src[e] : (e - E);
  int d = (e < E) ? dst[e] : (e - E);
  float4 j  = *(const float4*)(h + (long long)s * 64 + hd * 32 + q * 4);
  float4 i2 = *(const float4*)(h + (long long)d * 64 + hd * 32 + q * 4);
  float4 l  = *(const float4*)(attl + hd * 32 + q * 4);
  float4 r  = *(const float4*)(attr + hd * 32 + q * 4);
  float lg = j.x * i2.x + j.y * i2.y + j.z * i2.z + j.w * i2.w;
  float a  = j.x * l.x + j.y * l.y + j.z * l.z + j.w * l.w
           + i2.x * r.x + i2.y * r.y + i2.z * r.z + i2.w * r.w;
  lg += __shfl_xor(lg, 4); a += __shfl_xor(a, 4);
  lg += __shfl_xor(lg, 2); a += __shfl_xor(a, 2);
  lg += __shfl_xor(lg, 1); a += __shfl_xor(a, 1);
  if (q == 0) {
    float sg = 1.f / (1.f + __expf(-lg));
    a *= sg;
    a = (a > 0.f) ? a : 0.2f * a;  // leaky_relu 0.2
    alpha[g] = a;
    atomicMax(&mx[d * 2 + hd], enc_f(a));
  }
}

__global__ void k_expsum(const int* __restrict__ dst, float* __restrict__ alpha,
                         const unsigned* __restrict__ mx, float* __restrict__ sm,
                         int E, int N) {
  int idx = blockIdx.x * blockDim.x + threadIdx.x;
  int tot = (E + N) * 2;
  if (idx >= tot) return;
  int e = idx >> 1, hd = idx & 1;
  int d = (e < E) ? dst[e] : (e - E);
  float m = dec_f(mx[d * 2 + hd]);
  float ev = __expf(alpha[idx] - m);
  alpha[idx] = ev;
  atomicAdd(&sm[d * 2 + hd], ev);
}

// one thread per (edge, channel): head-fused mean accumulate into acc[N][32]
__global__ void k_scatter(const float* __restrict__ h, const int* __restrict__ src,
                          const int* __restrict__ dst, const float* __restrict__ alpha,
                          const float* __restrict__ sm, float* __restrict__ acc,
                          int E, int N) {
  long long tid = (long long)blockIdx.x * blockDim.x + threadIdx.x;
  long long tot = (long long)(E + N) * 32;
  if (tid >= tot) return;
  int e = (int)(tid >> 5);
  int c = (int)(tid & 31);
  int s = (e < E) ? src[e] : (e - E);
  int d = (e < E) ? dst[e] : (e - E);
  float a0 = alpha[e * 2] / sm[d * 2];
  float a1 = alpha[e * 2 + 1] / sm[d * 2 + 1];
  float v = 0.5f * (h[(long long)s * 64 + c] * a0 + h[(long long)s * 64 + 32 + c] * a1);
  atomicAdd(&acc[(long long)d * 32 + c], v);
}

// y = leaky(x2,0.01)+x2 where x2 = head-mean + bias; also BN partial sums
__global__ void k_finup(const float* __restrict__ acc, const float* __restrict__ gb,
                        float* __restrict__ y, float* __restrict__ bns, int N) {
  __shared__ float ls[64];
  if (threadIdx.x < 64) ls[threadIdx.x] = 0.f;
  __syncthreads();
  int tx = threadIdx.x & 31, ty = threadIdx.x >> 5;
  int base = blockIdx.x * 64;
  float ps = 0.f, pq = 0.f;
#pragma unroll
  for (int it = 0; it < 8; ++it) {
    int row = base + it * 8 + ty;
    if (row < N) {
      float v = acc[(long long)row * 32 + tx] + gb[tx];
      float yv = ((v > 0.f) ? v : 0.01f * v) + v;
      y[(long long)row * 32 + tx] = yv;
      ps += yv;
      pq += yv * yv;
    }
  }
  atomicAdd(&ls[tx], ps);
  atomicAdd(&ls[32 + tx], pq);
  __syncthreads();
  if (threadIdx.x < 64) atomicAdd(&bns[threadIdx.x], ls[threadIdx.x]);
}

// in-place safe (y may alias out)
__global__ void k_bnfinal(const float* __restrict__ y, const float* __restrict__ bns,
                          const float* __restrict__ g, const float* __restrict__ b,
                          float* __restrict__ out, int N) {
  int i = blockIdx.x * blockDim.x + threadIdx.x;
  if (i >= N * CC) return;
  int c = i & 31;
  float inv_n = 1.f / (float)N;
  float mu = bns[c] * inv_n;
  float var = bns[32 + c] * inv_n - mu * mu;
  out[i] = (y[i] - mu) * rsqrtf(var + 1e-5f) * g[c] + b[c];
}

extern "C" void kernel_launch(void* const* d_in, const int* in_sizes, int n_in,
                              void* d_out, int out_size, void* d_ws, size_t ws_size,
                              hipStream_t stream) {
  const float* patch = (const float*)d_in[0];
  const int* eidx = (const int*)d_in[1];
  // d_in[2] = edge_attr (unused by reference)
  const float* cheb_w = (const float*)d_in[3];
  const float* cheb_b = (const float*)d_in[4];
  const float* lin_w = (const float*)d_in[5];
  const float* att_l = (const float*)d_in[6];
  const float* att_r = (const float*)d_in[7];
  const float* gat_b = (const float*)d_in[8];
  const float* bn_g = (const float*)d_in[9];
  const float* bn_b = (const float*)d_in[10];
  float* out = (float*)d_out;

  const int N = in_sizes[0] / CC;   // 100000
  const int E = in_sizes[1] / 2;    // 1600000
  const int* src = eidx;
  const int* dst = eidx + E;

  // workspace layout (same 54.1 MB footprint as before; CSR aliases dead regions)
  float* f = (float*)d_ws;
  float* R2 = f;                             // N*32  (gat accmean)
  float* R0 = R2 + (size_t)N * 32;           // N*32  (Tx ping)
  float* R1 = R0 + (size_t)N * 32;           // N*32  (Tx pong; R0..R1 contiguous -> h[N*64])
  float* alpha = R1 + (size_t)N * 32;        // (E+N)*2
  unsigned* mx = (unsigned*)(alpha + (size_t)(E + N) * 2);  // N*2
  float* sm = (float*)(mx + (size_t)N * 2);  // N*2
  float* dis = sm + (size_t)N * 2;           // N
  float* bns = dis + N;                      // 64
  float* h = R0;                             // N*64 overlays R0..R1 after cheb
  // cheb-phase aliases (all dead before the GAT phase reuses the memory)
  int* ssrc = (int*)alpha;                   // E ints   (sorted-by-dst src)
  float* swt = alpha + E;                    // E floats (edge weights, -dis*dis)
  int* csum = (int*)(alpha + 2 * (size_t)E); // nb ints  (chunk sums)
  int* rptr = (int*)mx;                      // N+1 ints (CSR row ptr)
  int* cnt = (int*)sm;                       // N ints   (count, then cursor)

  const int B = 256;
  const long long NC = (long long)N * 32;

  // zero: R2 (gat acc); cnt..bns (CSR count + dis + bns)
  hipMemsetAsync(R2, 0, sizeof(float) * (size_t)N * 32, stream);
  hipMemsetAsync(sm, 0, sizeof(float) * ((size_t)N * 3 + 64), stream);

  // degree-by-src (for sym norm) + count-by-dst (for CSR) in one pass
  k_degcnt<<<cdiv(E, B), B, 0, stream>>>(src, dst, dis, cnt, E);
  k_dis<<<cdiv(N, B), B, 0, stream>>>(dis, N);

  // CSR build: rptr via chunked scan, then fill (bakes w_edge in)
  int nb = cdiv(N, CHUNK);
  k_chunksum<<<nb, B, 0, stream>>>(cnt, csum, N);
  k_scancsum<<<1, 1, 0, stream>>>(csum, nb, rptr, N, E);
  k_fillrptr<<<nb, B, 0, stream>>>(cnt, csum, rptr, N);
  k_fill<<<cdiv(E, B), B, 0, stream>>>(src, dst, dis, cnt, ssrc, swt, E);

  // ChebConv into d_out: k=0 dense, k=1..4 fused gather+recurrence+GEMM
  k_chebinit<<<cdiv(NC, B), B, 0, stream>>>(out, cheb_b, N * 32);
  k_gemm<32><<<cdiv(N, 8), B, 0, stream>>>(patch, cheb_w, out, N, 1);
  k_cheb<<<cdiv(N, 8), B, 0, stream>>>(patch, nullptr, rptr, ssrc, swt,
                                       cheb_w + 1024, 1.f, R0, out, N);
  k_cheb<<<cdiv(N, 8), B, 0, stream>>>(R0, patch, rptr, ssrc, swt,
                                       cheb_w + 2048, 2.f, R1, out, N);
  k_cheb<<<cdiv(N, 8), B, 0, stream>>>(R1, R0, rptr, ssrc, swt,
                                       cheb_w + 3072, 2.f, R0, out, N);
  k_cheb<<<cdiv(N, 8), B, 0, stream>>>(R0, R1, rptr, ssrc, swt,
                                       cheb_w + 4096, 2.f, R1, out, N);

  // SuperGAT: h = x @ lin_w  (x in d_out; h overlays R0..R1)
  k_gemm<64><<<cdiv(N, 4), B, 0, stream>>>(out, lin_w, h, N, 0);
  // re-zero sm (its memory served as the CSR cursor during the cheb phase)
  hipMemsetAsync(sm, 0, sizeof(float) * (size_t)N * 2, stream);
  k_mxinit<<<cdiv(N * 2, B), B, 0, stream>>>(mx, N * 2);
  long long tot8 = (long long)(E + N) * 2 * 8;
  k_alpha<<<cdiv(tot8, B), B, 0, stream>>>(h, src, dst, att_l, att_r, alpha, mx, E, N);
  int tot_eh = (E + N) * 2;
  k_expsum<<<cdiv(tot_eh, B), B, 0, stream>>>(dst, alpha, mx, sm, E, N);
  k_scatter<<<cdiv((long long)(E + N) * 32, B), B, 0, stream>>>(h, src, dst, alpha, sm,
                                                                R2, E, N);

  // y into d_out (x dead), BN stats, finalize in place
  k_finup<<<cdiv(N, 64), B, 0, stream>>>(R2, gat_b, out, bns, N);
  k_bnfinal<<<cdiv(NC, B), B, 0, stream>>>(out, bns, bn_g, bn_b, out, N);
}

// Round 2
// 993.403 us; speedup vs baseline: 1.5835x; 1.1481x over previous
//
#include <hip/hip_runtime.h>
#include <math.h>

#define CC 32
#define CHUNK 4096  // 256 threads * 16 elems, for the rptr scan

static inline int cdiv(long long a, int b) { return (int)((a + b - 1) / b); }

// ---------- degree (by src, float) + CSR count (by dst, int) in one pass ----------
// cnt is pre-initialized to 1 (the self-loop)
__global__ void k_degcnt(const int* __restrict__ src, const int* __restrict__ dst,
                         float* __restrict__ deg, int* __restrict__ cnt, int E) {
  int e = blockIdx.x * blockDim.x + threadIdx.x;
  if (e < E) {
    atomicAdd(&deg[src[e]], 1.0f);
    atomicAdd(&cnt[dst[e]], 1);
  }
}

__global__ void k_setone(int* __restrict__ cnt, int N) {
  int i = blockIdx.x * blockDim.x + threadIdx.x;
  if (i < N) cnt[i] = 1;
}

__global__ void k_dis(float* __restrict__ dis, int N) {
  int i = blockIdx.x * blockDim.x + threadIdx.x;
  if (i < N) {
    float d = dis[i];
    dis[i] = (d > 0.f) ? rsqrtf(fmaxf(d, 1.f)) : 0.f;
  }
}

// ---------- CSR build: chunk sums -> serial chunk scan -> per-chunk fill ----------
__global__ void k_chunksum(const int* __restrict__ cnt, int* __restrict__ csum, int N) {
  int base = blockIdx.x * CHUNK;
  int v = 0;
  for (int i = threadIdx.x; i < CHUNK; i += 256) {
    int idx = base + i;
    if (idx < N) v += cnt[idx];
  }
  for (int m = 32; m; m >>= 1) v += __shfl_xor(v, m);
  __shared__ int ws[4];
  if ((threadIdx.x & 63) == 0) ws[threadIdx.x >> 6] = v;
  __syncthreads();
  if (threadIdx.x == 0) csum[blockIdx.x] = ws[0] + ws[1] + ws[2] + ws[3];
}

__global__ void k_scancsum(int* __restrict__ csum, int nb, int* __restrict__ rptr,
                           int N, int tot) {
  int acc = 0;
  for (int i = 0; i < nb; ++i) { int v = csum[i]; csum[i] = acc; acc += v; }
  rptr[N] = tot;
}

// exclusive scan within chunk; writes rptr[i] and cursor (in-place over cnt)
__global__ void k_fillrptr(int* __restrict__ cnt, const int* __restrict__ csum,
                           int* __restrict__ rptr, int N) {
  int base = blockIdx.x * CHUNK + threadIdx.x * 16;
  int v[16];
  int tot = 0;
#pragma unroll
  for (int q = 0; q < 16; ++q) {
    int idx = base + q;
    v[q] = (idx < N) ? cnt[idx] : 0;
    tot += v[q];
  }
  __shared__ int sh[256];
  sh[threadIdx.x] = tot;
  __syncthreads();
  for (int off = 1; off < 256; off <<= 1) {
    int add = (threadIdx.x >= off) ? sh[threadIdx.x - off] : 0;
    __syncthreads();
    sh[threadIdx.x] += add;
    __syncthreads();
  }
  int excl = sh[threadIdx.x] - tot + csum[blockIdx.x];
#pragma unroll
  for (int q = 0; q < 16; ++q) {
    int idx = base + q;
    if (idx < N) { rptr[idx] = excl; cnt[idx] = excl; }
    excl += v[q];
  }
}

// fill E real edges (w = -dis*dis) + N self-loops (w = 0, used only by GAT)
__global__ void k_fill2(const int* __restrict__ src, const int* __restrict__ dst,
                        const float* __restrict__ dis, int* __restrict__ cursor,
                        int* __restrict__ gsrc, float* __restrict__ gw, int E, int N) {
  int e = blockIdx.x * blockDim.x + threadIdx.x;
  if (e >= E + N) return;
  int s, d; float w;
  if (e < E) {
    s = src[e]; d = dst[e];
    w = -dis[s] * dis[d];
  } else {
    s = d = e - E;
    w = 0.f;
  }
  int p = atomicAdd(&cursor[d], 1);
  gsrc[p] = s;
  gw[p] = w;
}

// ---------- fused Cheb step: gather-prop + recurrence + out += Tx@W ----------
// one 32-lane group per node; lane = channel (self-loop entries have w=0)
__global__ void k_cheb(const float* __restrict__ x_in, const float* __restrict__ x_sub,
                       const int* __restrict__ rptr, const int* __restrict__ ssrc,
                       const float* __restrict__ sw, const float* __restrict__ W,
                       float scale, float* __restrict__ tx_out, float* __restrict__ out,
                       int N) {
  __shared__ float wl[1024];
  for (int i = threadIdx.x; i < 1024; i += 256) wl[i] = W[i];
  __syncthreads();
  int node = blockIdx.x * 8 + (threadIdx.x >> 5);
  int lane = threadIdx.x & 31;
  if (node >= N) return;
  int beg = rptr[node], end = rptr[node + 1];
  float t = 0.f;
  for (int base = beg; base < end; base += 32) {
    int rem = end - base;
    int sj = 0; float wj = 0.f;
    if (lane < rem) { sj = ssrc[base + lane]; wj = sw[base + lane]; }
    int cnt = rem < 32 ? rem : 32;
#pragma unroll 4
    for (int q = 0; q < cnt; ++q) {
      int s = __shfl(sj, q, 32);
      float w = __shfl(wj, q, 32);
      t += w * x_in[(long long)s * 32 + lane];
    }
  }
  float txn = scale * t;
  if (x_sub) txn -= x_sub[(long long)node * 32 + lane];
  long long o = (long long)node * 32 + lane;
  tx_out[o] = txn;
  float acc = 0.f;
#pragma unroll
  for (int q = 0; q < 32; ++q)
    acc += __shfl(txn, q, 32) * wl[q * 32 + lane];
  out[o] += acc;
}

// out[i][j] (32-wide rows in T, OUTC-wide rows in out) (+)= T[i][:] @ W[32][OUTC]
template <int OUTC>
__global__ void k_gemm(const float* __restrict__ T, const float* __restrict__ W,
                       float* __restrict__ out, int N, int accumulate) {
  __shared__ float w[32 * OUTC];
  for (int i = threadIdx.x; i < 32 * OUTC; i += blockDim.x) w[i] = W[i];
  __syncthreads();
  const int ROWS = 256 / OUTC;
  int row = blockIdx.x * ROWS + threadIdx.x / OUTC;
  int col = threadIdx.x % OUTC;
  if (row >= N) return;
  const float* tr = T + (long long)row * 32;
  float acc = 0.f;
#pragma unroll
  for (int c = 0; c < 32; ++c) acc += tr[c] * w[c * OUTC + col];
  float* o = out + (long long)row * OUTC + col;
  if (accumulate) *o += acc; else *o = acc;
}

__global__ void k_chebinit(float* __restrict__ out, const float* __restrict__ b, int n) {
  int i = blockIdx.x * blockDim.x + threadIdx.x;
  if (i < n) out[i] = b[i & 31];
}

// ---------- fused SuperGAT: online-softmax gather + bias + head-mean +
// leaky+residual + BN partial sums. One 32-lane group per node; lane = channel.
__global__ void k_expgat(const float* __restrict__ h, const int* __restrict__ rptr,
                         const int* __restrict__ gsrc, const float* __restrict__ attl,
                         const float* __restrict__ attr, const float* __restrict__ gb,
                         float* __restrict__ y, float* __restrict__ bns, int N) {
  __shared__ float ls[64];
  for (int i = threadIdx.x; i < 64; i += 256) ls[i] = 0.f;
  __syncthreads();
  int node = blockIdx.x * 8 + (threadIdx.x >> 5);
  int lane = threadIdx.x & 31;
  if (node < N) {
    float l0 = attl[lane], l1 = attl[32 + lane];
    float r0 = attr[lane], r1 = attr[32 + lane];
    const float* hd_ = h + (long long)node * 64;
    float i0 = hd_[lane], i1 = hd_[32 + lane];
    // xi . att_r per head (butterfly over the 32-lane group)
    float ir0 = i0 * r0, ir1 = i1 * r1;
#pragma unroll
    for (int m = 16; m; m >>= 1) {
      ir0 += __shfl_xor(ir0, m, 32);
      ir1 += __shfl_xor(ir1, m, 32);
    }
    float m0 = -1e30f, m1 = -1e30f;
    float s0 = 0.f, s1 = 0.f, v0 = 0.f, v1 = 0.f;
    int beg = rptr[node], end = rptr[node + 1];
    for (int base = beg; base < end; base += 32) {
      int rem = end - base;
      int sj = (lane < rem) ? gsrc[base + lane] : 0;
      int cnt = rem < 32 ? rem : 32;
      for (int q = 0; q < cnt; ++q) {
        int s = __shfl(sj, q, 32);
        const float* hs = h + (long long)s * 64;
        float j0 = hs[lane], j1 = hs[32 + lane];
        float lg0 = j0 * i0, lg1 = j1 * i1;
        float a0 = j0 * l0, a1 = j1 * l1;
#pragma unroll
        for (int m = 16; m; m >>= 1) {
          lg0 += __shfl_xor(lg0, m, 32);
          lg1 += __shfl_xor(lg1, m, 32);
          a0 += __shfl_xor(a0, m, 32);
          a1 += __shfl_xor(a1, m, 32);
        }
        a0 = (a0 + ir0) / (1.f + __expf(-lg0));
        a1 = (a1 + ir1) / (1.f + __expf(-lg1));
        a0 = (a0 > 0.f) ? a0 : 0.2f * a0;  // leaky_relu 0.2
        a1 = (a1 > 0.f) ? a1 : 0.2f * a1;
        // online softmax rescale (uniform across the group -> no divergence)
        if (a0 > m0) { float r = __expf(m0 - a0); s0 *= r; v0 *= r; m0 = a0; }
        if (a1 > m1) { float r = __expf(m1 - a1); s1 *= r; v1 *= r; m1 = a1; }
        float e0 = __expf(a0 - m0), e1 = __expf(a1 - m1);
        s0 += e0; s1 += e1;
        v0 += e0 * j0; v1 += e1 * j1;
      }
    }
    float x2 = 0.5f * (v0 / s0 + v1 / s1) + gb[lane];
    float yv = ((x2 > 0.f) ? x2 : 0.01f * x2) + x2;  // leaky 0.01 + residual
    y[(long long)node * 32 + lane] = yv;
    atomicAdd(&ls[lane], yv);
    atomicAdd(&ls[32 + lane], yv * yv);
  }
  __syncthreads();
  if (threadIdx.x < 64) atomicAdd(&bns[threadIdx.x], ls[threadIdx.x]);
}

// in-place safe (y may alias out)
__global__ void k_bnfinal(const float* __restrict__ y, const float* __restrict__ bns,
                          const float* __restrict__ g, const float* __restrict__ b,
                          float* __restrict__ out, int N) {
  int i = blockIdx.x * blockDim.x + threadIdx.x;
  if (i >= N * CC) return;
  int c = i & 31;
  float inv_n = 1.f / (float)N;
  float mu = bns[c] * inv_n;
  float var = bns[32 + c] * inv_n - mu * mu;
  out[i] = (y[i] - mu) * rsqrtf(var + 1e-5f) * g[c] + b[c];
}

extern "C" void kernel_launch(void* const* d_in, const int* in_sizes, int n_in,
                              void* d_out, int out_size, void* d_ws, size_t ws_size,
                              hipStream_t stream) {
  const float* patch = (const float*)d_in[0];
  const int* eidx = (const int*)d_in[1];
  // d_in[2] = edge_attr (unused by reference)
  const float* cheb_w = (const float*)d_in[3];
  const float* cheb_b = (const float*)d_in[4];
  const float* lin_w = (const float*)d_in[5];
  const float* att_l = (const float*)d_in[6];
  const float* att_r = (const float*)d_in[7];
  const float* gat_b = (const float*)d_in[8];
  const float* bn_g = (const float*)d_in[9];
  const float* bn_b = (const float*)d_in[10];
  float* out = (float*)d_out;

  const int N = in_sizes[0] / CC;   // 100000
  const int E = in_sizes[1] / 2;    // 1600000
  const int* src = eidx;
  const int* dst = eidx + E;
  const int TOT = E + N;            // edges + self-loops, one shared CSR

  // workspace layout (~41 MB)
  float* R0 = (float*)d_ws;                  // N*32 (Tx ping; h = R0 as N*64)
  float* R1 = R0 + (size_t)N * 32;           // N*32 (Tx pong)
  float* gw = R1 + (size_t)N * 32;           // TOT floats (cheb weights, 0 on loops)
  int* gsrc = (int*)(gw + TOT);              // TOT ints (dst-sorted src)
  int* grptr = gsrc + TOT;                   // N+1 ints (CSR row ptr)
  int* cnt = grptr + (N + 1);                // N ints (count, then cursor)
  int* csum = cnt + N;                       // ~64 ints (chunk sums)
  float* dis = (float*)(csum + 64);          // N floats
  float* bns = dis + N;                      // 64 floats
  float* h = R0;                             // N*64 overlays R0..R1 after cheb

  const int B = 256;
  const long long NC = (long long)N * 32;

  hipMemsetAsync(dis, 0, sizeof(float) * ((size_t)N + 64), stream);  // dis, bns
  k_setone<<<cdiv(N, B), B, 0, stream>>>(cnt, N);

  // degree-by-src (sym norm) + count-by-dst (CSR, incl. self-loop) in one pass
  k_degcnt<<<cdiv(E, B), B, 0, stream>>>(src, dst, dis, cnt, E);
  k_dis<<<cdiv(N, B), B, 0, stream>>>(dis, N);

  // CSR build over E+N entries
  int nb = cdiv(N, CHUNK);
  k_chunksum<<<nb, B, 0, stream>>>(cnt, csum, N);
  k_scancsum<<<1, 1, 0, stream>>>(csum, nb, grptr, N, TOT);
  k_fillrptr<<<nb, B, 0, stream>>>(cnt, csum, grptr, N);
  k_fill2<<<cdiv(TOT, B), B, 0, stream>>>(src, dst, dis, cnt, gsrc, gw, E, N);

  // ChebConv into d_out: k=0 dense, k=1..4 fused gather+recurrence+GEMM
  k_chebinit<<<cdiv(NC, B), B, 0, stream>>>(out, cheb_b, N * 32);
  k_gemm<32><<<cdiv(N, 8), B, 0, stream>>>(patch, cheb_w, out, N, 1);
  k_cheb<<<cdiv(N, 8), B, 0, stream>>>(patch, nullptr, grptr, gsrc, gw,
                                       cheb_w + 1024, 1.f, R0, out, N);
  k_cheb<<<cdiv(N, 8), B, 0, stream>>>(R0, patch, grptr, gsrc, gw,
                                       cheb_w + 2048, 2.f, R1, out, N);
  k_cheb<<<cdiv(N, 8), B, 0, stream>>>(R1, R0, grptr, gsrc, gw,
                                       cheb_w + 3072, 2.f, R0, out, N);
  k_cheb<<<cdiv(N, 8), B, 0, stream>>>(R0, R1, grptr, gsrc, gw,
                                       cheb_w + 4096, 2.f, R1, out, N);

  // SuperGAT: h = x @ lin_w (x in d_out; h overlays R0..R1), then fused
  // online-softmax gather + epilogue + BN stats
  k_gemm<64><<<cdiv(N, 4), B, 0, stream>>>(out, lin_w, h, N, 0);
  k_expgat<<<cdiv(N, 8), B, 0, stream>>>(h, grptr, gsrc, att_l, att_r, gat_b,
                                         out, bns, N);
  k_bnfinal<<<cdiv(NC, B), B, 0, stream>>>(out, bns, bn_g, bn_b, out, N);
}